// Round 1
// baseline (572.316 us; speedup 1.0000x reference)
//
#include <hip/hip_runtime.h>
#include <stdint.h>

#define BB 4
#define SS 4096
#define HID 1024
#define NH 16
#define HD 64
#define TOKENS (BB * SS)  // 16384

typedef unsigned short u16;
typedef __bf16 bf16x8 __attribute__((ext_vector_type(8)));
typedef float f32x4 __attribute__((ext_vector_type(4)));
typedef __attribute__((address_space(1))) unsigned int u32g;
typedef __attribute__((address_space(3))) unsigned int u32l;

__device__ __forceinline__ u16 f2bf(float f) {
  union { float f; unsigned u; } v; v.f = f;
  unsigned u = v.u;
  unsigned r = u + 0x7fffu + ((u >> 16) & 1u);  // RNE
  return (u16)(r >> 16);
}
__device__ __forceinline__ float bf2f(u16 h) {
  union { unsigned u; float f; } v; v.u = ((unsigned)h) << 16;
  return v.f;
}

__device__ __forceinline__ void async16(const void* g, void* l) {
  __builtin_amdgcn_global_load_lds((const u32g*)g, (u32l*)l, 16, 0, 0);
}

// ---------------------------------------------------------------------------
// Transpose + cast: Wt[n][k] = bf16(W[k][n]), 1024x1024
// ---------------------------------------------------------------------------
__global__ __launch_bounds__(256) void transpose_cast(
    const float* __restrict__ W, u16* __restrict__ Wt) {
  __shared__ float t[32][33];
  const int bx = blockIdx.x * 32;  // n-tile
  const int by = blockIdx.y * 32;  // k-tile
  const int x = threadIdx.x;       // 0..31
#pragma unroll
  for (int yy = threadIdx.y; yy < 32; yy += 8)
    t[yy][x] = W[(size_t)(by + yy) * HID + bx + x];
  __syncthreads();
#pragma unroll
  for (int yy = threadIdx.y; yy < 32; yy += 8)
    Wt[(size_t)(bx + yy) * HID + by + x] = f2bf(t[x][yy]);
}

// ---------------------------------------------------------------------------
// GEMM: C[M,N] = A[M,K] @ Bt[N,K]^T + bias[N]
// A: fp32 (cast in staging) or bf16; Bt: bf16 N-major (pre-transposed W)
// 128x128 tile, 4 waves, each wave 64x64 via 4x4 of 16x16x32 bf16 MFMA
// M=16384, N=1024, K=1024 (exact divisibility assumed)
// ---------------------------------------------------------------------------
template <bool A_BF16, bool C_BF16>
__global__ __launch_bounds__(256, 2) void gemm_bt(
    const void* __restrict__ Av, const u16* __restrict__ Bt,
    const float* __restrict__ bias, void* __restrict__ Cv, int M, int N, int K) {
  __shared__ u16 As[128 * 32];
  __shared__ u16 Bs[128 * 32];
  const int tid = threadIdx.x;
  const int wave = tid >> 6, lane = tid & 63;
  const int quad = lane >> 4, l16 = lane & 15;
  const int m0 = blockIdx.y * 128, n0 = blockIdx.x * 128;
  const int wm = (wave >> 1) * 64, wn = (wave & 1) * 64;

  f32x4 acc[4][4] = {};

  for (int kt = 0; kt < K; kt += 32) {
    __syncthreads();
    // ---- B staging: async 16B chunks (wave-uniform LDS base + lane*16) ----
    {
      const u16* src = Bt + (size_t)n0 * K + kt;
#pragma unroll
      for (int is = 0; is < 2; ++is) {
        int g = is * 256 + wave * 64 + lane;  // chunk id (4 chunks / 32-elem row)
        const u16* gp = src + (size_t)(g >> 2) * K + (g & 3) * 8;
        u16* lp = &Bs[(is * 256 + wave * 64) * 8];
        async16(gp, lp);
      }
    }
    // ---- A staging ----
    if (A_BF16) {
      const u16* src = (const u16*)Av + (size_t)m0 * K + kt;
#pragma unroll
      for (int is = 0; is < 2; ++is) {
        int g = is * 256 + wave * 64 + lane;
        const u16* gp = src + (size_t)(g >> 2) * K + (g & 3) * 8;
        u16* lp = &As[(is * 256 + wave * 64) * 8];
        async16(gp, lp);
      }
    } else {
      const float* src = (const float*)Av + (size_t)m0 * K + kt;
#pragma unroll
      for (int c = 0; c < 4; ++c) {
        int g = c * 256 + tid;  // float4 chunk: 8 chunks per 32-float row
        int row = g >> 3, col = (g & 7) * 4;
        float4 f = *(const float4*)(src + (size_t)row * K + col);
        ushort4 h;
        h.x = f2bf(f.x); h.y = f2bf(f.y); h.z = f2bf(f.z); h.w = f2bf(f.w);
        *(ushort4*)&As[row * 32 + col] = h;
      }
    }
    __syncthreads();
    // ---- fragments + MFMA ----
    bf16x8 af[4], bfr[4];
#pragma unroll
    for (int i = 0; i < 4; ++i)
      af[i] = *(const bf16x8*)&As[(wm + i * 16 + l16) * 32 + quad * 8];
#pragma unroll
    for (int j = 0; j < 4; ++j)
      bfr[j] = *(const bf16x8*)&Bs[(wn + j * 16 + l16) * 32 + quad * 8];
#pragma unroll
    for (int i = 0; i < 4; ++i)
#pragma unroll
      for (int j = 0; j < 4; ++j)
        acc[i][j] = __builtin_amdgcn_mfma_f32_16x16x32_bf16(af[i], bfr[j],
                                                            acc[i][j], 0, 0, 0);
  }

  // ---- epilogue: D[row=quad*4+r][col=l16] ----
  const int cb = n0 + wn + l16;
#pragma unroll
  for (int i = 0; i < 4; ++i) {
    int rowb = m0 + wm + i * 16 + quad * 4;
#pragma unroll
    for (int j = 0; j < 4; ++j) {
      int col = cb + j * 16;
      float bv = bias[col];
#pragma unroll
      for (int r = 0; r < 4; ++r) {
        float v = acc[i][j][r] + bv;
        if (C_BF16)
          ((u16*)Cv)[(size_t)(rowb + r) * N + col] = f2bf(v);
        else
          ((float*)Cv)[(size_t)(rowb + r) * N + col] = v;
      }
    }
  }
}

// ---------------------------------------------------------------------------
// Per-token attention over the HEADS axis (16x16), one block per token.
// Writes attention probs (fp32, d_out part 1) and reordered o (bf16) at
// flat index b*S*HID + h*S*D + s*D + d (the torch transpose-then-view).
// ---------------------------------------------------------------------------
__global__ __launch_bounds__(256, 4) void attention_kernel(
    const u16* __restrict__ qb, const u16* __restrict__ kb,
    const u16* __restrict__ vb, const float* __restrict__ sw,
    float* __restrict__ attn_out, u16* __restrict__ o) {
  __shared__ float qs[16][65], ks[16][65], vs[16][65];
  __shared__ float sq[16], sk[16], qn[16], kn[16];
  __shared__ float attn_s[16][17];
  const int tid = threadIdx.x;
  const int token = blockIdx.x;
  const size_t base = (size_t)token * HID;

  {  // load q,k,v rows: 4 bf16 each per thread
    int idx = tid * 4;
    int h = idx >> 6, d = idx & 63;
    ushort4 uq = *(const ushort4*)(qb + base + idx);
    ushort4 uk = *(const ushort4*)(kb + base + idx);
    ushort4 uv = *(const ushort4*)(vb + base + idx);
    qs[h][d] = bf2f(uq.x); qs[h][d + 1] = bf2f(uq.y);
    qs[h][d + 2] = bf2f(uq.z); qs[h][d + 3] = bf2f(uq.w);
    ks[h][d] = bf2f(uk.x); ks[h][d + 1] = bf2f(uk.y);
    ks[h][d + 2] = bf2f(uk.z); ks[h][d + 3] = bf2f(uk.w);
    vs[h][d] = bf2f(uv.x); vs[h][d + 1] = bf2f(uv.y);
    vs[h][d + 2] = bf2f(uv.z); vs[h][d + 3] = bf2f(uv.w);
  }
  __syncthreads();

  if (tid < 32) {  // norms
    int i = tid & 15;
    const float* row = (tid < 16) ? qs[i] : ks[i];
    float s = 0.f;
#pragma unroll
    for (int d = 0; d < 64; ++d) s += row[d] * row[d];
    if (tid < 16) { sq[i] = s; qn[i] = sqrtf(s); }
    else          { sk[i] = s; kn[i] = sqrtf(s); }
  }
  __syncthreads();

  // score_weights softmax (3 values, computed redundantly per thread)
  float s0 = sw[0], s1 = sw[1], s2 = sw[2];
  float smx = fmaxf(s0, fmaxf(s1, s2));
  float e0 = expf(s0 - smx), e1 = expf(s1 - smx), e2 = expf(s2 - smx);
  float winv = 1.f / (e0 + e1 + e2);
  float w0 = e0 * winv, w1 = e1 * winv, w2 = e2 * winv;

  const int i = tid >> 4, j = tid & 15;
  float attn;
  {
    float dot = 0.f;
#pragma unroll
    for (int d = 0; d < 64; ++d) dot += qs[i][d] * ks[j][d];
    float sdot = dot * 0.125f;  // / sqrt(64)
    float cosv = dot / fmaxf(qn[i] * kn[j], 1e-8f);
    float d2 = fmaxf(sq[i] + sk[j] - 2.f * dot, 0.f);
    float dist = -sqrtf(d2);
    float score = w0 * sdot + w1 * cosv + w2 * dist;
    // softmax over j: width-16 groups within the wave
    float mx = score;
#pragma unroll
    for (int off = 8; off; off >>= 1) mx = fmaxf(mx, __shfl_xor(mx, off, 16));
    float e = expf(score - mx);
    float sum = e;
#pragma unroll
    for (int off = 8; off; off >>= 1) sum += __shfl_xor(sum, off, 16);
    attn = e / sum;
  }
  attn_out[(size_t)token * 256 + tid] = attn;  // coalesced: tid == i*16+j
  attn_s[i][j] = attn;
  __syncthreads();

  {  // o[i][d0..d0+3] = sum_j attn[i][j] * v[j][d0..d0+3]
    int d0 = j * 4;
    float o0 = 0.f, o1 = 0.f, o2 = 0.f, o3 = 0.f;
#pragma unroll
    for (int jj = 0; jj < 16; ++jj) {
      float a = attn_s[i][jj];
      o0 += a * vs[jj][d0];
      o1 += a * vs[jj][d0 + 1];
      o2 += a * vs[jj][d0 + 2];
      o3 += a * vs[jj][d0 + 3];
    }
    int b = token >> 12, s = token & (SS - 1);
    size_t off = (size_t)b * (SS * HID) + (size_t)i * (SS * HD) +
                 (size_t)s * HD + d0;
    ushort4 h;
    h.x = f2bf(o0); h.y = f2bf(o1); h.z = f2bf(o2); h.w = f2bf(o3);
    *(ushort4*)(o + off) = h;
  }
}

// ---------------------------------------------------------------------------
extern "C" void kernel_launch(void* const* d_in, const int* in_sizes, int n_in,
                              void* d_out, int out_size, void* d_ws,
                              size_t ws_size, hipStream_t stream) {
  (void)in_sizes; (void)n_in; (void)out_size; (void)ws_size;
  const float* query = (const float*)d_in[0];
  const float* key_  = (const float*)d_in[1];
  const float* value = (const float*)d_in[2];
  const float* Wq = (const float*)d_in[3];
  const float* bq = (const float*)d_in[4];
  const float* Wk = (const float*)d_in[5];
  const float* bk = (const float*)d_in[6];
  const float* Wv = (const float*)d_in[7];
  const float* bv = (const float*)d_in[8];
  const float* Wo = (const float*)d_in[9];
  const float* bo = (const float*)d_in[10];
  const float* sw = (const float*)d_in[11];

  char* ws = (char*)d_ws;
  u16* Wqt = (u16*)ws; ws += (size_t)HID * HID * 2;
  u16* Wkt = (u16*)ws; ws += (size_t)HID * HID * 2;
  u16* Wvt = (u16*)ws; ws += (size_t)HID * HID * 2;
  u16* Wot = (u16*)ws; ws += (size_t)HID * HID * 2;
  u16* qb = (u16*)ws; ws += (size_t)TOKENS * HID * 2;
  u16* kb = (u16*)ws; ws += (size_t)TOKENS * HID * 2;
  u16* vb = (u16*)ws; ws += (size_t)TOKENS * HID * 2;
  u16* ob = (u16*)ws; ws += (size_t)TOKENS * HID * 2;

  float* out0 = (float*)d_out;
  float* attn_out = out0 + (size_t)TOKENS * HID;

  dim3 tb(32, 8);
  dim3 tg(32, 32);
  transpose_cast<<<tg, tb, 0, stream>>>(Wq, Wqt);
  transpose_cast<<<tg, tb, 0, stream>>>(Wk, Wkt);
  transpose_cast<<<tg, tb, 0, stream>>>(Wv, Wvt);
  transpose_cast<<<tg, tb, 0, stream>>>(Wo, Wot);

  dim3 gg(HID / 128, TOKENS / 128);  // (8, 128)
  gemm_bt<false, true><<<gg, 256, 0, stream>>>(query, Wqt, bq, qb, TOKENS, HID, HID);
  gemm_bt<false, true><<<gg, 256, 0, stream>>>(key_, Wkt, bk, kb, TOKENS, HID, HID);
  gemm_bt<false, true><<<gg, 256, 0, stream>>>(value, Wvt, bv, vb, TOKENS, HID, HID);

  attention_kernel<<<TOKENS, 256, 0, stream>>>(qb, kb, vb, sw, attn_out, ob);

  gemm_bt<true, false><<<gg, 256, 0, stream>>>(ob, Wot, bo, out0, TOKENS, HID, HID);
}

// Round 2
// 506.737 us; speedup vs baseline: 1.1294x; 1.1294x over previous
//
#include <hip/hip_runtime.h>
#include <stdint.h>

#define BB 4
#define SS 4096
#define HID 1024
#define NH 16
#define HD 64
#define TOKENS (BB * SS)  // 16384

typedef unsigned short u16;
typedef __bf16 bf16x8 __attribute__((ext_vector_type(8)));
typedef float f32x4 __attribute__((ext_vector_type(4)));
typedef __attribute__((address_space(1))) unsigned int u32g;
typedef __attribute__((address_space(3))) unsigned int u32l;

__device__ __forceinline__ u16 f2bf(float f) {
  union { float f; unsigned u; } v; v.f = f;
  unsigned u = v.u;
  unsigned r = u + 0x7fffu + ((u >> 16) & 1u);  // RNE
  return (u16)(r >> 16);
}
__device__ __forceinline__ float bf2f(u16 h) {
  union { unsigned u; float f; } v; v.u = ((unsigned)h) << 16;
  return v.f;
}

__device__ __forceinline__ void async16(const void* g, void* l) {
  __builtin_amdgcn_global_load_lds((const u32g*)g, (u32l*)l, 16, 0, 0);
}

// ---------------------------------------------------------------------------
// Fused fp32->bf16 cast for q,k,v. Each thread: 8 floats -> 8 bf16 (16B store)
// grid: (TOKENS*HID/(256*8), 1, 3)
// ---------------------------------------------------------------------------
__global__ __launch_bounds__(256) void cast3_bf16(
    const float* __restrict__ q, const float* __restrict__ k,
    const float* __restrict__ v, u16* __restrict__ qo, u16* __restrict__ ko,
    u16* __restrict__ vo) {
  const int z = blockIdx.z;
  const float* s = (z == 0) ? q : (z == 1) ? k : v;
  u16* d = (z == 0) ? qo : (z == 1) ? ko : vo;
  size_t i = ((size_t)blockIdx.x * 256 + threadIdx.x) * 8;
  float4 f0 = *(const float4*)(s + i);
  float4 f1 = *(const float4*)(s + i + 4);
  ushort4 h0, h1;
  h0.x = f2bf(f0.x); h0.y = f2bf(f0.y); h0.z = f2bf(f0.z); h0.w = f2bf(f0.w);
  h1.x = f2bf(f1.x); h1.y = f2bf(f1.y); h1.z = f2bf(f1.z); h1.w = f2bf(f1.w);
  *(ushort4*)(d + i) = h0;
  *(ushort4*)(d + i + 4) = h1;
}

// ---------------------------------------------------------------------------
// Transpose + cast all four weights: Wt[n][k] = bf16(W[k][n]), 1024x1024, z=4
// ---------------------------------------------------------------------------
__global__ __launch_bounds__(256) void transpose_cast4(
    const float* __restrict__ W0, const float* __restrict__ W1,
    const float* __restrict__ W2, const float* __restrict__ W3,
    u16* __restrict__ T0, u16* __restrict__ T1, u16* __restrict__ T2,
    u16* __restrict__ T3) {
  const int z = blockIdx.z;
  const float* W = (z == 0) ? W0 : (z == 1) ? W1 : (z == 2) ? W2 : W3;
  u16* Wt = (z == 0) ? T0 : (z == 1) ? T1 : (z == 2) ? T2 : T3;
  __shared__ float t[32][33];
  const int bx = blockIdx.x * 32;  // n-tile
  const int by = blockIdx.y * 32;  // k-tile
  const int x = threadIdx.x;       // 0..31
#pragma unroll
  for (int yy = threadIdx.y; yy < 32; yy += 8)
    t[yy][x] = W[(size_t)(by + yy) * HID + bx + x];
  __syncthreads();
#pragma unroll
  for (int yy = threadIdx.y; yy < 32; yy += 8)
    Wt[(size_t)(bx + yy) * HID + by + x] = f2bf(t[x][yy]);
}

// ---------------------------------------------------------------------------
// GEMM: C[M,N] = A[M,K] @ Bt[N,K]^T + bias[N]; A,Bt bf16, C bf16 or fp32.
// 128x128 tile, 4 waves, 4x4 of 16x16x32 bf16 MFMA. BK=32.
// Grid: x = m-tile (fast), y = n-tile, optional z selects operand set.
// bid%8 == m%8 -> each XCD owns an m-stripe, reusing A-slabs in its L2.
// ---------------------------------------------------------------------------
template <bool C_BF16, int NZ>
__global__ __launch_bounds__(256, 4) void gemm_bt(
    const u16* __restrict__ A0, const u16* __restrict__ A1,
    const u16* __restrict__ A2, const u16* __restrict__ B0,
    const u16* __restrict__ B1, const u16* __restrict__ B2,
    const float* __restrict__ bias0, const float* __restrict__ bias1,
    const float* __restrict__ bias2, void* __restrict__ C0,
    void* __restrict__ C1, void* __restrict__ C2, int M, int N, int K) {
  const u16* A = A0;
  const u16* Bt = B0;
  const float* bias = bias0;
  void* Cv = C0;
  if (NZ > 1) {
    int z = blockIdx.z;
    A = (z == 0) ? A0 : (z == 1) ? A1 : A2;
    Bt = (z == 0) ? B0 : (z == 1) ? B1 : B2;
    bias = (z == 0) ? bias0 : (z == 1) ? bias1 : bias2;
    Cv = (z == 0) ? C0 : (z == 1) ? C1 : C2;
  }
  __shared__ u16 As[128 * 32];
  __shared__ u16 Bs[128 * 32];
  const int tid = threadIdx.x;
  const int wave = tid >> 6, lane = tid & 63;
  const int quad = lane >> 4, l16 = lane & 15;
  const int m0 = blockIdx.x * 128, n0 = blockIdx.y * 128;
  const int wm = (wave >> 1) * 64, wn = (wave & 1) * 64;

  f32x4 acc[4][4] = {};

  for (int kt = 0; kt < K; kt += 32) {
    __syncthreads();
    // ---- staging: async 16B chunks (wave-uniform LDS base + lane*16) ----
    {
      const u16* srcB = Bt + (size_t)n0 * K + kt;
      const u16* srcA = A + (size_t)m0 * K + kt;
#pragma unroll
      for (int is = 0; is < 2; ++is) {
        int g = is * 256 + wave * 64 + lane;  // chunk id (4 chunks/row)
        const u16* gpB = srcB + (size_t)(g >> 2) * K + (g & 3) * 8;
        const u16* gpA = srcA + (size_t)(g >> 2) * K + (g & 3) * 8;
        async16(gpB, &Bs[(is * 256 + wave * 64) * 8]);
        async16(gpA, &As[(is * 256 + wave * 64) * 8]);
      }
    }
    __syncthreads();
    // ---- fragments + MFMA ----
    bf16x8 af[4], bfr[4];
#pragma unroll
    for (int i = 0; i < 4; ++i)
      af[i] = *(const bf16x8*)&As[(wm + i * 16 + l16) * 32 + quad * 8];
#pragma unroll
    for (int j = 0; j < 4; ++j)
      bfr[j] = *(const bf16x8*)&Bs[(wn + j * 16 + l16) * 32 + quad * 8];
#pragma unroll
    for (int i = 0; i < 4; ++i)
#pragma unroll
      for (int j = 0; j < 4; ++j)
        acc[i][j] = __builtin_amdgcn_mfma_f32_16x16x32_bf16(af[i], bfr[j],
                                                            acc[i][j], 0, 0, 0);
  }

  // ---- epilogue: D[row=quad*4+r][col=l16] ----
  const int cb = n0 + wn + l16;
#pragma unroll
  for (int i = 0; i < 4; ++i) {
    int rowb = m0 + wm + i * 16 + quad * 4;
#pragma unroll
    for (int j = 0; j < 4; ++j) {
      int col = cb + j * 16;
      float bv = bias[col];
#pragma unroll
      for (int r = 0; r < 4; ++r) {
        float v = acc[i][j][r] + bv;
        if (C_BF16)
          ((u16*)Cv)[(size_t)(rowb + r) * N + col] = f2bf(v);
        else
          ((float*)Cv)[(size_t)(rowb + r) * N + col] = v;
      }
    }
  }
}

// ---------------------------------------------------------------------------
// Per-token attention over the HEADS axis (16x16), one block per token.
// Writes attention probs (fp32) and reordered o (bf16) at flat index
// b*S*HID + h*S*D + s*D + d (the torch transpose-then-view).
// ---------------------------------------------------------------------------
__global__ __launch_bounds__(256, 4) void attention_kernel(
    const u16* __restrict__ qb, const u16* __restrict__ kb,
    const u16* __restrict__ vb, const float* __restrict__ sw,
    float* __restrict__ attn_out, u16* __restrict__ o) {
  __shared__ float qs[16][65], ks[16][65], vs[16][65];
  __shared__ float sq[16], sk[16], qn[16], kn[16];
  __shared__ float attn_s[16][17];
  const int tid = threadIdx.x;
  const int token = blockIdx.x;
  const size_t base = (size_t)token * HID;

  {  // load q,k,v rows: 4 bf16 each per thread
    int idx = tid * 4;
    int h = idx >> 6, d = idx & 63;
    ushort4 uq = *(const ushort4*)(qb + base + idx);
    ushort4 uk = *(const ushort4*)(kb + base + idx);
    ushort4 uv = *(const ushort4*)(vb + base + idx);
    qs[h][d] = bf2f(uq.x); qs[h][d + 1] = bf2f(uq.y);
    qs[h][d + 2] = bf2f(uq.z); qs[h][d + 3] = bf2f(uq.w);
    ks[h][d] = bf2f(uk.x); ks[h][d + 1] = bf2f(uk.y);
    ks[h][d + 2] = bf2f(uk.z); ks[h][d + 3] = bf2f(uk.w);
    vs[h][d] = bf2f(uv.x); vs[h][d + 1] = bf2f(uv.y);
    vs[h][d + 2] = bf2f(uv.z); vs[h][d + 3] = bf2f(uv.w);
  }
  __syncthreads();

  if (tid < 32) {  // norms
    int i = tid & 15;
    const float* row = (tid < 16) ? qs[i] : ks[i];
    float s = 0.f;
#pragma unroll
    for (int d = 0; d < 64; ++d) s += row[d] * row[d];
    if (tid < 16) { sq[i] = s; qn[i] = sqrtf(s); }
    else          { sk[i] = s; kn[i] = sqrtf(s); }
  }
  __syncthreads();

  // score_weights softmax (3 values, computed redundantly per thread)
  float s0 = sw[0], s1 = sw[1], s2 = sw[2];
  float smx = fmaxf(s0, fmaxf(s1, s2));
  float e0 = expf(s0 - smx), e1 = expf(s1 - smx), e2 = expf(s2 - smx);
  float winv = 1.f / (e0 + e1 + e2);
  float w0 = e0 * winv, w1 = e1 * winv, w2 = e2 * winv;

  const int i = tid >> 4, j = tid & 15;
  float attn;
  {
    float dot = 0.f;
#pragma unroll
    for (int d = 0; d < 64; ++d) dot += qs[i][d] * ks[j][d];
    float sdot = dot * 0.125f;  // / sqrt(64)
    float cosv = dot / fmaxf(qn[i] * kn[j], 1e-8f);
    float d2 = fmaxf(sq[i] + sk[j] - 2.f * dot, 0.f);
    float dist = -sqrtf(d2);
    float score = w0 * sdot + w1 * cosv + w2 * dist;
    // softmax over j: width-16 groups within the wave
    float mx = score;
#pragma unroll
    for (int off = 8; off; off >>= 1) mx = fmaxf(mx, __shfl_xor(mx, off, 16));
    float e = expf(score - mx);
    float sum = e;
#pragma unroll
    for (int off = 8; off; off >>= 1) sum += __shfl_xor(sum, off, 16);
    attn = e / sum;
  }
  attn_out[(size_t)token * 256 + tid] = attn;  // coalesced: tid == i*16+j
  attn_s[i][j] = attn;
  __syncthreads();

  {  // o[i][d0..d0+3] = sum_j attn[i][j] * v[j][d0..d0+3]
    int d0 = j * 4;
    float o0 = 0.f, o1 = 0.f, o2 = 0.f, o3 = 0.f;
#pragma unroll
    for (int jj = 0; jj < 16; ++jj) {
      float a = attn_s[i][jj];
      o0 += a * vs[jj][d0];
      o1 += a * vs[jj][d0 + 1];
      o2 += a * vs[jj][d0 + 2];
      o3 += a * vs[jj][d0 + 3];
    }
    int b = token >> 12, s = token & (SS - 1);
    size_t off = (size_t)b * (SS * HID) + (size_t)i * (SS * HD) +
                 (size_t)s * HD + d0;
    ushort4 h;
    h.x = f2bf(o0); h.y = f2bf(o1); h.z = f2bf(o2); h.w = f2bf(o3);
    *(ushort4*)(o + off) = h;
  }
}

// ---------------------------------------------------------------------------
extern "C" void kernel_launch(void* const* d_in, const int* in_sizes, int n_in,
                              void* d_out, int out_size, void* d_ws,
                              size_t ws_size, hipStream_t stream) {
  (void)in_sizes; (void)n_in; (void)out_size; (void)ws_size;
  const float* query = (const float*)d_in[0];
  const float* key_  = (const float*)d_in[1];
  const float* value = (const float*)d_in[2];
  const float* Wq = (const float*)d_in[3];
  const float* bq = (const float*)d_in[4];
  const float* Wk = (const float*)d_in[5];
  const float* bk = (const float*)d_in[6];
  const float* Wv = (const float*)d_in[7];
  const float* bv = (const float*)d_in[8];
  const float* Wo = (const float*)d_in[9];
  const float* bo = (const float*)d_in[10];
  const float* sw = (const float*)d_in[11];

  char* ws = (char*)d_ws;
  u16* Wqt = (u16*)ws; ws += (size_t)HID * HID * 2;
  u16* Wkt = (u16*)ws; ws += (size_t)HID * HID * 2;
  u16* Wvt = (u16*)ws; ws += (size_t)HID * HID * 2;
  u16* Wot = (u16*)ws; ws += (size_t)HID * HID * 2;
  u16* qh = (u16*)ws; ws += (size_t)TOKENS * HID * 2;  // bf16 inputs
  u16* kh = (u16*)ws; ws += (size_t)TOKENS * HID * 2;
  u16* vh = (u16*)ws; ws += (size_t)TOKENS * HID * 2;
  u16* qb = (u16*)ws; ws += (size_t)TOKENS * HID * 2;  // projections
  u16* kb = (u16*)ws; ws += (size_t)TOKENS * HID * 2;
  u16* vb = (u16*)ws; ws += (size_t)TOKENS * HID * 2;
  u16* ob = (u16*)ws; ws += (size_t)TOKENS * HID * 2;

  float* out0 = (float*)d_out;
  float* attn_out = out0 + (size_t)TOKENS * HID;

  transpose_cast4<<<dim3(32, 32, 4), dim3(32, 8), 0, stream>>>(
      Wq, Wk, Wv, Wo, Wqt, Wkt, Wvt, Wot);

  cast3_bf16<<<dim3(TOKENS * HID / (256 * 8), 1, 3), 256, 0, stream>>>(
      query, key_, value, qh, kh, vh);

  // fused QKV projections: grid x=m (fast, ->XCD stripe), y=n, z=proj
  gemm_bt<true, 3><<<dim3(TOKENS / 128, HID / 128, 3), 256, 0, stream>>>(
      qh, kh, vh, Wqt, Wkt, Wvt, bq, bk, bv, qb, kb, vb, TOKENS, HID, HID);

  attention_kernel<<<TOKENS, 256, 0, stream>>>(qb, kb, vb, sw, attn_out, ob);

  gemm_bt<false, 1><<<dim3(TOKENS / 128, HID / 128, 1), 256, 0, stream>>>(
      ob, nullptr, nullptr, Wot, nullptr, nullptr, bo, nullptr, nullptr,
      out0, nullptr, nullptr, TOKENS, HID, HID);
}

// Round 3
// 462.929 us; speedup vs baseline: 1.2363x; 1.0946x over previous
//
#include <hip/hip_runtime.h>
#include <stdint.h>

#define BB 4
#define SS 4096
#define HID 1024
#define NH 16
#define HD 64
#define TOKENS (BB * SS)  // 16384

typedef unsigned short u16;
typedef __bf16 bf16x8 __attribute__((ext_vector_type(8)));
typedef u16 u16x8 __attribute__((ext_vector_type(8)));
typedef float f32x4 __attribute__((ext_vector_type(4)));
typedef __attribute__((address_space(1))) unsigned int u32g;
typedef __attribute__((address_space(3))) unsigned int u32l;

__device__ __forceinline__ u16 f2bf(float f) {
  union { float f; unsigned u; } v; v.f = f;
  unsigned u = v.u;
  unsigned r = u + 0x7fffu + ((u >> 16) & 1u);  // RNE
  return (u16)(r >> 16);
}
__device__ __forceinline__ float bf2f(u16 h) {
  union { unsigned u; float f; } v; v.u = ((unsigned)h) << 16;
  return v.f;
}
__device__ __forceinline__ unsigned pack2(float a, float b) {
  return (unsigned)f2bf(a) | ((unsigned)f2bf(b) << 16);
}

__device__ __forceinline__ void async16(const void* g, void* l) {
  __builtin_amdgcn_global_load_lds((const u32g*)g, (u32l*)l, 16, 0, 0);
}

// ---------------------------------------------------------------------------
// Transpose + cast all four weights: Wt[n][k] = bf16(W[k][n]), 1024x1024, z=4
// ---------------------------------------------------------------------------
__global__ __launch_bounds__(256) void transpose_cast4(
    const float* __restrict__ W0, const float* __restrict__ W1,
    const float* __restrict__ W2, const float* __restrict__ W3,
    u16* __restrict__ T0, u16* __restrict__ T1, u16* __restrict__ T2,
    u16* __restrict__ T3) {
  const int z = blockIdx.z;
  const float* W = (z == 0) ? W0 : (z == 1) ? W1 : (z == 2) ? W2 : W3;
  u16* Wt = (z == 0) ? T0 : (z == 1) ? T1 : (z == 2) ? T2 : T3;
  __shared__ float t[32][33];
  const int bx = blockIdx.x * 32;  // n-tile
  const int by = blockIdx.y * 32;  // k-tile
  const int x = threadIdx.x;       // 0..31
#pragma unroll
  for (int yy = threadIdx.y; yy < 32; yy += 8)
    t[yy][x] = W[(size_t)(by + yy) * HID + bx + x];
  __syncthreads();
#pragma unroll
  for (int yy = threadIdx.y; yy < 32; yy += 8)
    Wt[(size_t)(bx + yy) * HID + by + x] = f2bf(t[x][yy]);
}

// ---------------------------------------------------------------------------
// LDS layouts (both GEMMs): tile [128 rows][32 k] bf16, row = 64 B = 4 chunks
// of 16 B. Chunk slot for k-chunk q of row r is  q ^ ((r>>1)&3)  -> frag
// ds_read_b128's tile all 32 banks (2-way = free) instead of 8-way conflicts.
// ---------------------------------------------------------------------------

// GEMM-QKV: C[M,N] = bf16(A_fp32)[M,K] @ Bt[N,K]^T + bias; z selects q/k/v.
// Grid x = m-tile (fast -> bid%8 = m%8 -> per-XCD A-slab reuse), y = n, z = 3.
__global__ __launch_bounds__(256, 4) void gemm_qkv(
    const float* __restrict__ A0, const float* __restrict__ A1,
    const float* __restrict__ A2, const u16* __restrict__ B0,
    const u16* __restrict__ B1, const u16* __restrict__ B2,
    const float* __restrict__ bias0, const float* __restrict__ bias1,
    const float* __restrict__ bias2, u16* __restrict__ C0,
    u16* __restrict__ C1, u16* __restrict__ C2) {
  const int z = blockIdx.z;
  const float* A = (z == 0) ? A0 : (z == 1) ? A1 : A2;
  const u16* Bt = (z == 0) ? B0 : (z == 1) ? B1 : B2;
  const float* bias = (z == 0) ? bias0 : (z == 1) ? bias1 : bias2;
  u16* Cv = (z == 0) ? C0 : (z == 1) ? C1 : C2;
  const int K = HID, N = HID;

  __shared__ u16 As[128 * 32];
  __shared__ u16 Bs[128 * 32];
  const int tid = threadIdx.x;
  const int wave = tid >> 6, lane = tid & 63;
  const int quad = lane >> 4, l16 = lane & 15;
  const int m0 = blockIdx.x * 128, n0 = blockIdx.y * 128;
  const int wm = (wave >> 1) * 64, wn = (wave & 1) * 64;
  const int sw_frag = ((l16 >> 1) & 3);  // (row>>1)&3 for frag rows

  f32x4 acc[4][4] = {};

  for (int kt = 0; kt < K; kt += 32) {
    __syncthreads();
    // ---- B staging: async16, swizzle applied to SOURCE chunk ----
    {
      const u16* srcB = Bt + (size_t)n0 * K + kt;
#pragma unroll
      for (int is = 0; is < 2; ++is) {
        int slot = is * 256 + wave * 64 + lane;  // LDS dest chunk (fixed)
        int row = slot >> 2, c = slot & 3;
        int cg = c ^ ((row >> 1) & 3);
        async16(srcB + (size_t)row * K + cg * 8,
                &Bs[(is * 256 + wave * 64) * 8]);
      }
    }
    // ---- A staging: fp32 global -> bf16 -> swizzled ds_write_b128 ----
    {
      const float* srcA = A + (size_t)m0 * K + kt;
#pragma unroll
      for (int c2 = 0; c2 < 2; ++c2) {
        int g = c2 * 256 + tid;  // chunk of 8 elems
        int row = g >> 2, cc = g & 3;
        const float* gp = srcA + (size_t)row * K + cc * 8;
        float4 f0 = *(const float4*)gp;
        float4 f1 = *(const float4*)(gp + 4);
        u16x8 h;
        h[0] = f2bf(f0.x); h[1] = f2bf(f0.y); h[2] = f2bf(f0.z);
        h[3] = f2bf(f0.w); h[4] = f2bf(f1.x); h[5] = f2bf(f1.y);
        h[6] = f2bf(f1.z); h[7] = f2bf(f1.w);
        int cs = cc ^ ((row >> 1) & 3);
        *(u16x8*)&As[row * 32 + cs * 8] = h;
      }
    }
    __syncthreads();
    // ---- fragments + MFMA ----
    bf16x8 af[4], bfr[4];
#pragma unroll
    for (int i = 0; i < 4; ++i)
      af[i] = *(const bf16x8*)&As[(wm + i * 16 + l16) * 32 +
                                  (quad ^ sw_frag) * 8];
#pragma unroll
    for (int j = 0; j < 4; ++j)
      bfr[j] = *(const bf16x8*)&Bs[(wn + j * 16 + l16) * 32 +
                                   (quad ^ sw_frag) * 8];
#pragma unroll
    for (int i = 0; i < 4; ++i)
#pragma unroll
      for (int j = 0; j < 4; ++j)
        acc[i][j] = __builtin_amdgcn_mfma_f32_16x16x32_bf16(af[i], bfr[j],
                                                            acc[i][j], 0, 0, 0);
  }

  // ---- epilogue: D[row=quad*4+r][col=l16] ----
  const int cb = n0 + wn + l16;
#pragma unroll
  for (int i = 0; i < 4; ++i) {
    int rowb = m0 + wm + i * 16 + quad * 4;
#pragma unroll
    for (int j = 0; j < 4; ++j) {
      int col = cb + j * 16;
      float bv = bias[col];
#pragma unroll
      for (int r = 0; r < 4; ++r)
        Cv[(size_t)(rowb + r) * N + col] = f2bf(acc[i][j][r] + bv);
    }
  }
}

// GEMM-AO: C_fp32[M,N] = A_bf16[M,K] @ Bt[N,K]^T + bias (final projection)
__global__ __launch_bounds__(256, 4) void gemm_ao(
    const u16* __restrict__ A, const u16* __restrict__ Bt,
    const float* __restrict__ bias, float* __restrict__ Cv) {
  const int K = HID, N = HID;
  __shared__ u16 As[128 * 32];
  __shared__ u16 Bs[128 * 32];
  const int tid = threadIdx.x;
  const int wave = tid >> 6, lane = tid & 63;
  const int quad = lane >> 4, l16 = lane & 15;
  const int m0 = blockIdx.x * 128, n0 = blockIdx.y * 128;
  const int wm = (wave >> 1) * 64, wn = (wave & 1) * 64;
  const int sw_frag = ((l16 >> 1) & 3);

  f32x4 acc[4][4] = {};

  for (int kt = 0; kt < K; kt += 32) {
    __syncthreads();
    const u16* srcB = Bt + (size_t)n0 * K + kt;
    const u16* srcA = A + (size_t)m0 * K + kt;
#pragma unroll
    for (int is = 0; is < 2; ++is) {
      int slot = is * 256 + wave * 64 + lane;
      int row = slot >> 2, c = slot & 3;
      int cg = c ^ ((row >> 1) & 3);
      async16(srcB + (size_t)row * K + cg * 8, &Bs[(is * 256 + wave * 64) * 8]);
      async16(srcA + (size_t)row * K + cg * 8, &As[(is * 256 + wave * 64) * 8]);
    }
    __syncthreads();
    bf16x8 af[4], bfr[4];
#pragma unroll
    for (int i = 0; i < 4; ++i)
      af[i] = *(const bf16x8*)&As[(wm + i * 16 + l16) * 32 +
                                  (quad ^ sw_frag) * 8];
#pragma unroll
    for (int j = 0; j < 4; ++j)
      bfr[j] = *(const bf16x8*)&Bs[(wn + j * 16 + l16) * 32 +
                                   (quad ^ sw_frag) * 8];
#pragma unroll
    for (int i = 0; i < 4; ++i)
#pragma unroll
      for (int j = 0; j < 4; ++j)
        acc[i][j] = __builtin_amdgcn_mfma_f32_16x16x32_bf16(af[i], bfr[j],
                                                            acc[i][j], 0, 0, 0);
  }

  const int cb = n0 + wn + l16;
#pragma unroll
  for (int i = 0; i < 4; ++i) {
    int rowb = m0 + wm + i * 16 + quad * 4;
#pragma unroll
    for (int j = 0; j < 4; ++j) {
      int col = cb + j * 16;
      float bv = bias[col];
#pragma unroll
      for (int r = 0; r < 4; ++r)
        Cv[(size_t)(rowb + r) * N + col] = acc[i][j][r] + bv;
    }
  }
}

// ---------------------------------------------------------------------------
// Attention: ONE WAVE PER TOKEN. QK^T via 2x mfma_16x16x32_bf16 with frags
// loaded straight from global (coalesced 16B/lane). Norms/softmax via shfl.
// Only per-wave LDS: attn 16x17 fp32, V 16x68 fp32. One barrier.
// Writes attn probs fp32 and o (bf16) at b*S*HID + h*S*D + s*D + d.
// ---------------------------------------------------------------------------
__global__ __launch_bounds__(256) void attention_mfma(
    const u16* __restrict__ qb, const u16* __restrict__ kb,
    const u16* __restrict__ vb, const float* __restrict__ sw,
    float* __restrict__ attn_out, u16* __restrict__ o) {
  __shared__ float vs_s[4][16 * 68];    // per-wave V fp32 (row stride 68)
  __shared__ float at_s[4][16 * 17];    // per-wave attn (row stride 17)
  const int tid = threadIdx.x;
  const int wave = tid >> 6, lane = tid & 63;
  const int quad = lane >> 4, l16 = lane & 15;
  const int token = blockIdx.x * 4 + wave;
  const size_t base = (size_t)token * HID;

  // Q/K fragments direct from global: A[m=l16][k=quad*8+j]
  const u16* qp = qb + base + l16 * 64 + quad * 8;
  const u16* kp = kb + base + l16 * 64 + quad * 8;
  bf16x8 aq0 = *(const bf16x8*)qp;
  bf16x8 aq1 = *(const bf16x8*)(qp + 32);
  bf16x8 bk0 = *(const bf16x8*)kp;
  bf16x8 bk1 = *(const bf16x8*)(kp + 32);

  // Stage V -> LDS fp32 (wave-private): lane loads 16 bf16 = 32 B
  float* vsw = vs_s[wave];
  {
    const u16* vp = vb + base + lane * 16;
    u16x8 h0 = *(const u16x8*)vp;
    u16x8 h1 = *(const u16x8*)(vp + 8);
    int row = lane >> 2, d0 = (lane & 3) * 16;
    float* dst = vsw + row * 68 + d0;
#pragma unroll
    for (int c = 0; c < 8; ++c) { dst[c] = bf2f(h0[c]); dst[8 + c] = bf2f(h1[c]); }
  }

  // QK^T
  f32x4 c = {};
  c = __builtin_amdgcn_mfma_f32_16x16x32_bf16(aq0, bk0, c, 0, 0, 0);
  c = __builtin_amdgcn_mfma_f32_16x16x32_bf16(aq1, bk1, c, 0, 0, 0);

  // Row sums of squares from frags; reduce over quads (lanes l16+16q)
  float sq = 0.f, sk = 0.f;
#pragma unroll
  for (int jj = 0; jj < 8; ++jj) {
    float a0 = (float)aq0[jj], a1 = (float)aq1[jj];
    float b0 = (float)bk0[jj], b1 = (float)bk1[jj];
    sq += a0 * a0 + a1 * a1;
    sk += b0 * b0 + b1 * b1;
  }
  sq += __shfl_xor(sq, 16); sq += __shfl_xor(sq, 32);  // sq_full[l16]
  sk += __shfl_xor(sk, 16); sk += __shfl_xor(sk, 32);  // sk_full[l16]

  // score-weight softmax (redundant per lane)
  float s0 = sw[0], s1 = sw[1], s2 = sw[2];
  float smx = fmaxf(s0, fmaxf(s1, s2));
  float e0 = __expf(s0 - smx), e1 = __expf(s1 - smx), e2 = __expf(s2 - smx);
  float winv = 1.f / (e0 + e1 + e2);
  float w0 = e0 * winv, w1 = e1 * winv, w2 = e2 * winv;

  // scores + softmax over cols (reg r = row quad*4+r, col = l16)
  const float kn = sqrtf(sk);
  float attn[4];
#pragma unroll
  for (int r = 0; r < 4; ++r) {
    float sqr = __shfl(sq, (lane & 48) + quad * 4 + r);  // sq[row]
    float dot = c[r];
    float sdot = dot * 0.125f;
    float cosv = dot / fmaxf(sqrtf(sqr) * kn, 1e-8f);
    float d2 = fmaxf(sqr + sk - 2.f * dot, 0.f);
    float score = w0 * sdot + w1 * cosv - w2 * sqrtf(d2);
    float mx = score;
#pragma unroll
    for (int off = 8; off; off >>= 1) mx = fmaxf(mx, __shfl_xor(mx, off, 16));
    float e = __expf(score - mx);
    float sum = e;
#pragma unroll
    for (int off = 8; off; off >>= 1) sum += __shfl_xor(sum, off, 16);
    attn[r] = e / sum;
  }

  // store probs (fp32 output) + to LDS for the PV product
  float* atw = at_s[wave];
#pragma unroll
  for (int r = 0; r < 4; ++r) {
    int row = quad * 4 + r;
    attn_out[(size_t)token * 256 + row * 16 + l16] = attn[r];
    atw[row * 17 + l16] = attn[r];
  }
  __syncthreads();

  // O[i=l16][d = quad*16 + c] = sum_j attn[i][j] * V[j][d]
  float acc[16];
#pragma unroll
  for (int cc = 0; cc < 16; ++cc) acc[cc] = 0.f;
  const int d0 = quad * 16;
  const float* arow = atw + l16 * 17;
#pragma unroll
  for (int j = 0; j < 16; ++j) {
    float a = arow[j];
    const float* vr = vsw + j * 68 + d0;
    float4 v0 = *(const float4*)vr;
    float4 v1 = *(const float4*)(vr + 4);
    float4 v2 = *(const float4*)(vr + 8);
    float4 v3 = *(const float4*)(vr + 12);
    acc[0] += a * v0.x;  acc[1] += a * v0.y;  acc[2] += a * v0.z;  acc[3] += a * v0.w;
    acc[4] += a * v1.x;  acc[5] += a * v1.y;  acc[6] += a * v1.z;  acc[7] += a * v1.w;
    acc[8] += a * v2.x;  acc[9] += a * v2.y;  acc[10] += a * v2.z; acc[11] += a * v2.w;
    acc[12] += a * v3.x; acc[13] += a * v3.y; acc[14] += a * v3.z; acc[15] += a * v3.w;
  }
  // store 16 bf16 = 2x uint4 at b*S*HID + i*S*64 + s*64 + d0
  {
    int b = token >> 12, s = token & (SS - 1);
    size_t off = (size_t)b * (SS * HID) + (size_t)l16 * (SS * HD) +
                 (size_t)s * HD + d0;
    uint4 p0, p1;
    p0.x = pack2(acc[0], acc[1]);   p0.y = pack2(acc[2], acc[3]);
    p0.z = pack2(acc[4], acc[5]);   p0.w = pack2(acc[6], acc[7]);
    p1.x = pack2(acc[8], acc[9]);   p1.y = pack2(acc[10], acc[11]);
    p1.z = pack2(acc[12], acc[13]); p1.w = pack2(acc[14], acc[15]);
    *(uint4*)(o + off) = p0;
    *(uint4*)(o + off + 8) = p1;
  }
}

// ---------------------------------------------------------------------------
extern "C" void kernel_launch(void* const* d_in, const int* in_sizes, int n_in,
                              void* d_out, int out_size, void* d_ws,
                              size_t ws_size, hipStream_t stream) {
  (void)in_sizes; (void)n_in; (void)out_size; (void)ws_size;
  const float* query = (const float*)d_in[0];
  const float* key_  = (const float*)d_in[1];
  const float* value = (const float*)d_in[2];
  const float* Wq = (const float*)d_in[3];
  const float* bq = (const float*)d_in[4];
  const float* Wk = (const float*)d_in[5];
  const float* bk = (const float*)d_in[6];
  const float* Wv = (const float*)d_in[7];
  const float* bv = (const float*)d_in[8];
  const float* Wo = (const float*)d_in[9];
  const float* bo = (const float*)d_in[10];
  const float* sw = (const float*)d_in[11];

  char* ws = (char*)d_ws;
  u16* Wqt = (u16*)ws; ws += (size_t)HID * HID * 2;
  u16* Wkt = (u16*)ws; ws += (size_t)HID * HID * 2;
  u16* Wvt = (u16*)ws; ws += (size_t)HID * HID * 2;
  u16* Wot = (u16*)ws; ws += (size_t)HID * HID * 2;
  u16* qb = (u16*)ws; ws += (size_t)TOKENS * HID * 2;  // projections (bf16)
  u16* kb = (u16*)ws; ws += (size_t)TOKENS * HID * 2;
  u16* vb = (u16*)ws; ws += (size_t)TOKENS * HID * 2;
  u16* ob = (u16*)ws; ws += (size_t)TOKENS * HID * 2;  // attn output, reordered

  float* out0 = (float*)d_out;
  float* attn_out = out0 + (size_t)TOKENS * HID;

  transpose_cast4<<<dim3(32, 32, 4), dim3(32, 8), 0, stream>>>(
      Wq, Wk, Wv, Wo, Wqt, Wkt, Wvt, Wot);

  // fused QKV projections: fp32 A in-kernel cast; x=m (XCD stripe), y=n, z=qkv
  gemm_qkv<<<dim3(TOKENS / 128, HID / 128, 3), 256, 0, stream>>>(
      query, key_, value, Wqt, Wkt, Wvt, bq, bk, bv, qb, kb, vb);

  attention_mfma<<<TOKENS / 4, 256, 0, stream>>>(qb, kb, vb, sw, attn_out, ob);

  gemm_ao<<<dim3(TOKENS / 128, HID / 128, 1), 256, 0, stream>>>(
      ob, Wot, bo, out0);
}